// Round 5
// baseline (303.409 us; speedup 1.0000x reference)
//
#include <hip/hip_runtime.h>

// Problem constants: N=32, C=3, H=W=512, SCALE=1 -> OUT=512, A=512,
// DENSE=4 -> thr0 = 4.0, ITERS=5.
#define NB   32
#define NC   3
#define HH   512
#define WW   512
#define AA   512
#define OUT  512

// clang ext_vector types — accepted by __builtin_nontemporal_store
typedef float vf4 __attribute__((ext_vector_type(4)));
typedef float vf2 __attribute__((ext_vector_type(2)));

// ---------------- wave-level primitives (64-lane) ---------------------------
__device__ __forceinline__ float wave_sum(float v) {
#pragma unroll
    for (int m = 32; m > 0; m >>= 1) v += __shfl_xor(v, m, 64);
    return v;
}
__device__ __forceinline__ float wave_max(float v) {
#pragma unroll
    for (int m = 32; m > 0; m >>= 1) v = fmaxf(v, __shfl_xor(v, m, 64));
    return v;
}

// ---------------- kernel 1: iterative clip + inverse CDF --------------------
// ONE WAVE per batch n; everything in registers except the final cumsum,
// which goes to LDS for the binary search. (Verified correct in R1.)
__global__ __launch_bounds__(64) void clip_cdf_kernel(
    const float* __restrict__ attx, const float* __restrict__ atty,
    float* __restrict__ px, float* __restrict__ py)
{
    __shared__ float csx[AA];
    __shared__ float csy[AA];

    const int n    = blockIdx.x;
    const int lane = threadIdx.x;          // 0..63

    float ax[8], ay[8];
    {
        const float4* bx = (const float4*)(attx + n * AA + lane * 8);
        const float4* by = (const float4*)(atty + n * AA + lane * 8);
        float4 x0 = bx[0], x1 = bx[1];
        float4 yv0 = by[0], yv1 = by[1];
        ax[0]=x0.x; ax[1]=x0.y; ax[2]=x0.z; ax[3]=x0.w;
        ax[4]=x1.x; ax[5]=x1.y; ax[6]=x1.z; ax[7]=x1.w;
        ay[0]=yv0.x; ay[1]=yv0.y; ay[2]=yv0.z; ay[3]=yv0.w;
        ay[4]=yv1.x; ay[5]=yv1.y; ay[6]=yv1.z; ay[7]=yv1.w;
    }

    {
        float lsx = 0.0f, lsy = 0.0f;
#pragma unroll
        for (int k = 0; k < 8; ++k) { lsx += ax[k]; lsy += ay[k]; }
        const float sx = wave_sum(lsx);
        const float sy = wave_sum(lsy);
#pragma unroll
        for (int k = 0; k < 8; ++k) {
            ax[k] = ax[k] / sx * (float)OUT;
            ay[k] = ay[k] / sy * (float)OUT;
        }
    }

#pragma unroll
    for (int it = 0; it < 5; ++it) {
        float lmx = ax[0], lmy = ay[0];
#pragma unroll
        for (int k = 1; k < 8; ++k) { lmx = fmaxf(lmx, ax[k]); lmy = fmaxf(lmy, ay[k]); }
        const float mx = wave_max(lmx);
        const float my = wave_max(lmy);
        float tv = fminf(mx, my);
        if (it == 0) tv = fminf(tv, 4.0f);     // thr0 = DENSE*OUT/A

        float lsx = 0.0f, lsy = 0.0f;
#pragma unroll
        for (int k = 0; k < 8; ++k) {
            ax[k] = fminf(ax[k], tv); lsx += ax[k];
            ay[k] = fminf(ay[k], tv); lsy += ay[k];
        }
        const float sxs = wave_sum(lsx);
        const float sys = wave_sum(lsy);
        const float addx = ((float)OUT - sxs) * (1.0f / (float)AA);
        const float addy = ((float)OUT - sys) * (1.0f / (float)AA);
#pragma unroll
        for (int k = 0; k < 8; ++k) { ax[k] += addx; ay[k] += addy; }
    }

    float prex[8], prey[8];
    float runx = 0.0f, runy = 0.0f;
#pragma unroll
    for (int k = 0; k < 8; ++k) {
        runx += ax[k]; prex[k] = runx;
        runy += ay[k]; prey[k] = runy;
    }
    const float ltx = runx, lty = runy;
    float sxi = ltx, syi = lty;
#pragma unroll
    for (int off = 1; off < 64; off <<= 1) {
        const float tx = __shfl_up(sxi, off, 64);
        const float ty = __shfl_up(syi, off, 64);
        if (lane >= off) { sxi += tx; syi += ty; }
    }
    const float exx  = sxi - ltx;
    const float exy  = syi - lty;
    const float totx = __shfl(sxi, 63, 64);
    const float toty = __shfl(syi, 63, 64);

#pragma unroll
    for (int k = 0; k < 8; ++k) {
        csx[lane * 8 + k] = exx + prex[k];
        csy[lane * 8 + k] = exy + prey[k];
    }
    __syncthreads();

    const float stepx = totx * (1.0f / (float)OUT);
    const float stepy = toty * (1.0f / (float)OUT);

    float rx[8], ry[8];
#pragma unroll
    for (int k = 0; k < 8; ++k) {
        const int e = lane * 8 + k;
        {
            const float tk = ((float)e + 0.5f) * stepx;
            int lo = 0, hi = AA;
            while (lo < hi) {
                const int mid = (lo + hi) >> 1;
                if (csx[mid] < tk) lo = mid + 1; else hi = mid;
            }
            int j = lo > AA - 1 ? AA - 1 : lo;
            const float cp   = (j > 0) ? csx[j - 1] : 0.0f;
            const float dens = csx[j] - cp;
            const float p    = (float)j + (tk - cp) / fmaxf(dens, 1e-6f);
            rx[k] = 2.0f * p / (float)AA - 1.0f;
        }
        {
            const float tk = ((float)e + 0.5f) * stepy;
            int lo = 0, hi = AA;
            while (lo < hi) {
                const int mid = (lo + hi) >> 1;
                if (csy[mid] < tk) lo = mid + 1; else hi = mid;
            }
            int j = lo > AA - 1 ? AA - 1 : lo;
            const float cp   = (j > 0) ? csy[j - 1] : 0.0f;
            const float dens = csy[j] - cp;
            const float p    = (float)j + (tk - cp) / fmaxf(dens, 1e-6f);
            ry[k] = 2.0f * p / (float)AA - 1.0f;
        }
    }

    float4* opx = (float4*)(px + n * OUT + lane * 8);
    float4* opy = (float4*)(py + n * OUT + lane * 8);
    opx[0] = make_float4(rx[0], rx[1], rx[2], rx[3]);
    opx[1] = make_float4(rx[4], rx[5], rx[6], rx[7]);
    opy[0] = make_float4(ry[0], ry[1], ry[2], ry[3]);
    opy[1] = make_float4(ry[4], ry[5], ry[6], ry[7]);
}

// ---------------- kernel 2: grid build + bilinear sample -------------------
// NO LDS staging, NO barriers: the per-n working set (3 MB) is L2-resident
// (4 MB/XCD, XCD swizzle keeps each n's rows on one XCD), and the gather
// indices x0(j) ~= j are monotone => direct global gathers are nearly
// coalesced and L1 absorbs the x0/x0+1 overlap. Outputs use nontemporal
// stores so 167.8 MB of writes don't evict the data rows from L2.
__global__ __launch_bounds__(256) void sample_kernel(
    const float* __restrict__ data, const float* __restrict__ px,
    const float* __restrict__ py, float* __restrict__ sampled,
    float2* __restrict__ grid)
{
    // bijective chunked XCD swizzle: 16384 blocks, 8 XCDs, 2048-block chunks.
    int b = blockIdx.x;
    b = (b & 7) * ((NB * OUT) / 8) + (b >> 3);
    const int n = b >> 9;                // / 512
    const int i = b & (OUT - 1);

    const int tid = threadIdx.x;

    const float gy  = py[n * OUT + i];
    const float iy  = (gy + 1.0f) * 0.5f * (float)(HH - 1);
    const float y0f = floorf(iy);
    const float wy  = iy - y0f;
    int y0 = (int)y0f;
    y0 = max(0, min(y0, HH - 1));
    const int y1 = min(y0 + 1, HH - 1);
    const float omwy = 1.0f - wy;

    const float* dbase = data + (size_t)n * NC * HH * WW;
    const float* r0 = dbase + (size_t)y0 * WW;   // + c*HH*WW per channel
    const float* r1 = dbase + (size_t)y1 * WW;

    // two adjacent outputs per thread: j = 2*tid, 2*tid+1
    const float2 g2 = ((const float2*)(px + n * OUT))[tid];

    const float ix0 = (g2.x + 1.0f) * 0.5f * (float)(WW - 1);
    const float ix1 = (g2.y + 1.0f) * 0.5f * (float)(WW - 1);
    const float xf0 = floorf(ix0);
    const float xf1 = floorf(ix1);
    const float wx0 = ix0 - xf0;
    const float wx1 = ix1 - xf1;
    int a0 = (int)xf0; a0 = max(0, min(a0, WW - 1)); const int b0 = min(a0 + 1, WW - 1);
    int a1 = (int)xf1; a1 = max(0, min(a1, WW - 1)); const int b1 = min(a1 + 1, WW - 1);
    const float omx0 = 1.0f - wx0;
    const float omx1 = 1.0f - wx1;

    float* sbase  = sampled + (size_t)n * NC * HH * WW + (size_t)i * WW;
    vf4*   gbase4 = (vf4*)(grid + ((size_t)n * OUT + i) * OUT);
    {
        vf4 g4; g4.x = g2.x; g4.y = gy; g4.z = g2.y; g4.w = gy;
        __builtin_nontemporal_store(g4, gbase4 + tid);
    }

#pragma unroll
    for (int c = 0; c < NC; ++c) {
        const float* c0 = r0 + (size_t)c * HH * WW;
        const float* c1 = r1 + (size_t)c * HH * WW;

        const float v00a = c0[a0];
        const float v01a = c0[b0];
        const float v10a = c1[a0];
        const float v11a = c1[b0];
        const float v00b = c0[a1];
        const float v01b = c0[b1];
        const float v10b = c1[a1];
        const float v11b = c1[b1];

        const float topa = v00a * omx0 + v01a * wx0;
        const float bota = v10a * omx0 + v11a * wx0;
        const float topb = v00b * omx1 + v01b * wx1;
        const float botb = v10b * omx1 + v11b * wx1;

        const float ra = topa * omwy + bota * wy;
        const float rb = topb * omwy + botb * wy;

        vf2 s2; s2.x = ra; s2.y = rb;
        __builtin_nontemporal_store(s2, (vf2*)(sbase + (size_t)c * HH * WW) + tid);
    }
}

extern "C" void kernel_launch(void* const* d_in, const int* in_sizes, int n_in,
                              void* d_out, int out_size, void* d_ws, size_t ws_size,
                              hipStream_t stream) {
    const float* data = (const float*)d_in[0];
    const float* attx = (const float*)d_in[1];
    const float* atty = (const float*)d_in[2];

    float* px = (float*)d_ws;                 // NB*OUT floats
    float* py = px + NB * OUT;                // NB*OUT floats

    float*  out     = (float*)d_out;
    float*  sampled = out;                                        // (N,C,H,W)
    float2* grid    = (float2*)(out + (size_t)NB * NC * HH * WW); // (N,H,W,2)

    clip_cdf_kernel<<<NB, 64, 0, stream>>>(attx, atty, px, py);
    sample_kernel<<<NB * OUT, 256, 0, stream>>>(data, px, py, sampled, grid);
}

// Round 7
// 251.556 us; speedup vs baseline: 1.2061x; 1.2061x over previous
//
#include <hip/hip_runtime.h>

// Problem constants: N=32, C=3, H=W=512, SCALE=1 -> OUT=512, A=512,
// DENSE=4 -> thr0 = 4.0, ITERS=5.
#define NB   32
#define NC   3
#define HH   512
#define WW   512
#define AA   512
#define OUT  512

// clang ext_vector types — accepted by __builtin_nontemporal_store
typedef float vf2 __attribute__((ext_vector_type(2)));

// ---------------- wave-level primitives (64-lane) ---------------------------
__device__ __forceinline__ float wave_sum(float v) {
#pragma unroll
    for (int m = 32; m > 0; m >>= 1) v += __shfl_xor(v, m, 64);
    return v;
}
__device__ __forceinline__ float wave_max(float v) {
#pragma unroll
    for (int m = 32; m > 0; m >>= 1) v = fmaxf(v, __shfl_xor(v, m, 64));
    return v;
}

// ---------------- kernel 1: iterative clip + inverse CDF --------------------
// ONE WAVE per batch n; everything in registers except the final cumsum,
// which goes to LDS for the binary search. (Verified correct R1/R5, ~5-10us.)
__global__ __launch_bounds__(64) void clip_cdf_kernel(
    const float* __restrict__ attx, const float* __restrict__ atty,
    float* __restrict__ px, float* __restrict__ py)
{
    __shared__ float csx[AA];
    __shared__ float csy[AA];

    const int n    = blockIdx.x;
    const int lane = threadIdx.x;          // 0..63

    float ax[8], ay[8];
    {
        const float4* bx = (const float4*)(attx + n * AA + lane * 8);
        const float4* by = (const float4*)(atty + n * AA + lane * 8);
        float4 x0 = bx[0], x1 = bx[1];
        float4 yv0 = by[0], yv1 = by[1];
        ax[0]=x0.x; ax[1]=x0.y; ax[2]=x0.z; ax[3]=x0.w;
        ax[4]=x1.x; ax[5]=x1.y; ax[6]=x1.z; ax[7]=x1.w;
        ay[0]=yv0.x; ay[1]=yv0.y; ay[2]=yv0.z; ay[3]=yv0.w;
        ay[4]=yv1.x; ay[5]=yv1.y; ay[6]=yv1.z; ay[7]=yv1.w;
    }

    {
        float lsx = 0.0f, lsy = 0.0f;
#pragma unroll
        for (int k = 0; k < 8; ++k) { lsx += ax[k]; lsy += ay[k]; }
        const float sx = wave_sum(lsx);
        const float sy = wave_sum(lsy);
#pragma unroll
        for (int k = 0; k < 8; ++k) {
            ax[k] = ax[k] / sx * (float)OUT;
            ay[k] = ay[k] / sy * (float)OUT;
        }
    }

#pragma unroll
    for (int it = 0; it < 5; ++it) {
        float lmx = ax[0], lmy = ay[0];
#pragma unroll
        for (int k = 1; k < 8; ++k) { lmx = fmaxf(lmx, ax[k]); lmy = fmaxf(lmy, ay[k]); }
        const float mx = wave_max(lmx);
        const float my = wave_max(lmy);
        float tv = fminf(mx, my);
        if (it == 0) tv = fminf(tv, 4.0f);     // thr0 = DENSE*OUT/A

        float lsx = 0.0f, lsy = 0.0f;
#pragma unroll
        for (int k = 0; k < 8; ++k) {
            ax[k] = fminf(ax[k], tv); lsx += ax[k];
            ay[k] = fminf(ay[k], tv); lsy += ay[k];
        }
        const float sxs = wave_sum(lsx);
        const float sys = wave_sum(lsy);
        const float addx = ((float)OUT - sxs) * (1.0f / (float)AA);
        const float addy = ((float)OUT - sys) * (1.0f / (float)AA);
#pragma unroll
        for (int k = 0; k < 8; ++k) { ax[k] += addx; ay[k] += addy; }
    }

    float prex[8], prey[8];
    float runx = 0.0f, runy = 0.0f;
#pragma unroll
    for (int k = 0; k < 8; ++k) {
        runx += ax[k]; prex[k] = runx;
        runy += ay[k]; prey[k] = runy;
    }
    const float ltx = runx, lty = runy;
    float sxi = ltx, syi = lty;
#pragma unroll
    for (int off = 1; off < 64; off <<= 1) {
        const float tx = __shfl_up(sxi, off, 64);
        const float ty = __shfl_up(syi, off, 64);
        if (lane >= off) { sxi += tx; syi += ty; }
    }
    const float exx  = sxi - ltx;
    const float exy  = syi - lty;
    const float totx = __shfl(sxi, 63, 64);
    const float toty = __shfl(syi, 63, 64);

#pragma unroll
    for (int k = 0; k < 8; ++k) {
        csx[lane * 8 + k] = exx + prex[k];
        csy[lane * 8 + k] = exy + prey[k];
    }
    __syncthreads();

    const float stepx = totx * (1.0f / (float)OUT);
    const float stepy = toty * (1.0f / (float)OUT);

    float rx[8], ry[8];
#pragma unroll
    for (int k = 0; k < 8; ++k) {
        const int e = lane * 8 + k;
        {
            const float tk = ((float)e + 0.5f) * stepx;
            int lo = 0, hi = AA;
            while (lo < hi) {
                const int mid = (lo + hi) >> 1;
                if (csx[mid] < tk) lo = mid + 1; else hi = mid;
            }
            int j = lo > AA - 1 ? AA - 1 : lo;
            const float cp   = (j > 0) ? csx[j - 1] : 0.0f;
            const float dens = csx[j] - cp;
            const float p    = (float)j + (tk - cp) / fmaxf(dens, 1e-6f);
            rx[k] = 2.0f * p / (float)AA - 1.0f;
        }
        {
            const float tk = ((float)e + 0.5f) * stepy;
            int lo = 0, hi = AA;
            while (lo < hi) {
                const int mid = (lo + hi) >> 1;
                if (csy[mid] < tk) lo = mid + 1; else hi = mid;
            }
            int j = lo > AA - 1 ? AA - 1 : lo;
            const float cp   = (j > 0) ? csy[j - 1] : 0.0f;
            const float dens = csy[j] - cp;
            const float p    = (float)j + (tk - cp) / fmaxf(dens, 1e-6f);
            ry[k] = 2.0f * p / (float)AA - 1.0f;
        }
    }

    float4* opx = (float4*)(px + n * OUT + lane * 8);
    float4* opy = (float4*)(py + n * OUT + lane * 8);
    opx[0] = make_float4(rx[0], rx[1], rx[2], rx[3]);
    opx[1] = make_float4(rx[4], rx[5], rx[6], rx[7]);
    opy[0] = make_float4(ry[0], ry[1], ry[2], ry[3]);
    opy[1] = make_float4(ry[4], ry[5], ry[6], ry[7]);
}

// ---------------- kernel 2: grid build + bilinear sample -------------------
// R0-exact staged structure (best measured: ~66us inside a 253.9 total),
// plus two targeted fixes:
//  (a) ALL output stores nontemporal -> no L2 write-allocate thrash from the
//      167.8 MB write stream (keeps staged rows resident).
//  (b) px loads + grid stores hoisted BEFORE the barrier (they don't depend
//      on LDS), overlapping the staging loads in flight.
// No XCD swizzle (R0, the fastest variant, had none).
__global__ __launch_bounds__(256) void sample_kernel(
    const float* __restrict__ data, const float* __restrict__ px,
    const float* __restrict__ py, float* __restrict__ sampled,
    float2* __restrict__ grid)
{
    __shared__ float lrow[6][WW];   // 12 KB: rows (y0,c0..2), (y1,c0..2)

    const int bid = blockIdx.x;          // n*OUT + i
    const int n   = bid >> 9;            // / 512
    const int i   = bid & (OUT - 1);
    const int tid = threadIdx.x;

    const float gy  = py[n * OUT + i];
    // hoisted px loads (independent of staging)
    const float gx0 = px[n * OUT + tid];
    const float gx1 = px[n * OUT + tid + 256];

    const float iy  = (gy + 1.0f) * 0.5f * (float)(HH - 1);
    const float y0f = floorf(iy);
    const float wy  = iy - y0f;
    int y0 = (int)y0f;
    y0 = max(0, min(y0, HH - 1));
    const int y1 = min(y0 + 1, HH - 1);
    const float omwy = 1.0f - wy;

    const float* dbase = data + (size_t)n * NC * HH * WW;

    // stage 6 rows: 768 float4s over 256 threads (3 each), coalesced
#pragma unroll
    for (int k = 0; k < 3; ++k) {
        const int idx = tid + k * 256;       // 0..767
        const int row = idx >> 7;            // 0..5 (128 float4 per row)
        const int q   = idx & 127;           // float4 index within row
        const int c   = (row < 3) ? row : row - 3;
        const int y   = (row < 3) ? y0 : y1;
        const float4 v = ((const float4*)(dbase + ((size_t)c * HH + y) * WW))[q];
        ((float4*)&lrow[row][0])[q] = v;
    }

    // grid stores before the barrier: independent of LDS, overlap staging
    vf2* gbase2 = (vf2*)(grid + ((size_t)n * OUT + i) * OUT);
    {
        vf2 g0; g0.x = gx0; g0.y = gy;
        vf2 g1; g1.x = gx1; g1.y = gy;
        __builtin_nontemporal_store(g0, gbase2 + tid);
        __builtin_nontemporal_store(g1, gbase2 + tid + 256);
    }

    __syncthreads();

    float* sbase = sampled + (size_t)n * NC * HH * WW + (size_t)i * WW;

#pragma unroll
    for (int rep = 0; rep < 2; ++rep) {
        const int j = tid + rep * 256;
        const float gx  = (rep == 0) ? gx0 : gx1;
        const float ix  = (gx + 1.0f) * 0.5f * (float)(WW - 1);
        const float x0f = floorf(ix);
        const float wx  = ix - x0f;
        int x0 = (int)x0f;
        x0 = max(0, min(x0, WW - 1));
        const int x1 = min(x0 + 1, WW - 1);
        const float omwx = 1.0f - wx;

#pragma unroll
        for (int c = 0; c < NC; ++c) {
            const float v00 = lrow[c][x0];
            const float v01 = lrow[c][x1];
            const float v10 = lrow[3 + c][x0];
            const float v11 = lrow[3 + c][x1];
            const float top = v00 * omwx + v01 * wx;
            const float bot = v10 * omwx + v11 * wx;
            const float r   = top * omwy + bot * wy;
            __builtin_nontemporal_store(r, sbase + (size_t)c * HH * WW + j);
        }
    }
}

extern "C" void kernel_launch(void* const* d_in, const int* in_sizes, int n_in,
                              void* d_out, int out_size, void* d_ws, size_t ws_size,
                              hipStream_t stream) {
    const float* data = (const float*)d_in[0];
    const float* attx = (const float*)d_in[1];
    const float* atty = (const float*)d_in[2];

    float* px = (float*)d_ws;                 // NB*OUT floats
    float* py = px + NB * OUT;                // NB*OUT floats

    float*  out     = (float*)d_out;
    float*  sampled = out;                                        // (N,C,H,W)
    float2* grid    = (float2*)(out + (size_t)NB * NC * HH * WW); // (N,H,W,2)

    clip_cdf_kernel<<<NB, 64, 0, stream>>>(attx, atty, px, py);
    sample_kernel<<<NB * OUT, 256, 0, stream>>>(data, px, py, sampled, grid);
}

// Round 8
// 250.620 us; speedup vs baseline: 1.2106x; 1.0037x over previous
//
#include <hip/hip_runtime.h>

// Problem constants: N=32, C=3, H=W=512, SCALE=1 -> OUT=512, A=512,
// DENSE=4 -> thr0 = 4.0, ITERS=5.
#define NB   32
#define NC   3
#define HH   512
#define WW   512
#define AA   512
#define OUT  512

// clang ext_vector types — accepted by __builtin_nontemporal_store
typedef float vf2 __attribute__((ext_vector_type(2)));

// ---------------- wave-level primitives (64-lane) ---------------------------
__device__ __forceinline__ float wave_sum(float v) {
#pragma unroll
    for (int m = 32; m > 0; m >>= 1) v += __shfl_xor(v, m, 64);
    return v;
}
__device__ __forceinline__ float wave_max(float v) {
#pragma unroll
    for (int m = 32; m > 0; m >>= 1) v = fmaxf(v, __shfl_xor(v, m, 64));
    return v;
}

// ---------------- kernel 1: iterative clip + inverse CDF --------------------
// ONE WAVE per batch n; everything in registers except the final cumsum,
// which goes to LDS for the binary search. (Verified correct R1/R5/R7.)
__global__ __launch_bounds__(64) void clip_cdf_kernel(
    const float* __restrict__ attx, const float* __restrict__ atty,
    float* __restrict__ px, float* __restrict__ py)
{
    __shared__ float csx[AA];
    __shared__ float csy[AA];

    const int n    = blockIdx.x;
    const int lane = threadIdx.x;          // 0..63

    float ax[8], ay[8];
    {
        const float4* bx = (const float4*)(attx + n * AA + lane * 8);
        const float4* by = (const float4*)(atty + n * AA + lane * 8);
        float4 x0 = bx[0], x1 = bx[1];
        float4 yv0 = by[0], yv1 = by[1];
        ax[0]=x0.x; ax[1]=x0.y; ax[2]=x0.z; ax[3]=x0.w;
        ax[4]=x1.x; ax[5]=x1.y; ax[6]=x1.z; ax[7]=x1.w;
        ay[0]=yv0.x; ay[1]=yv0.y; ay[2]=yv0.z; ay[3]=yv0.w;
        ay[4]=yv1.x; ay[5]=yv1.y; ay[6]=yv1.z; ay[7]=yv1.w;
    }

    {
        float lsx = 0.0f, lsy = 0.0f;
#pragma unroll
        for (int k = 0; k < 8; ++k) { lsx += ax[k]; lsy += ay[k]; }
        const float sx = wave_sum(lsx);
        const float sy = wave_sum(lsy);
#pragma unroll
        for (int k = 0; k < 8; ++k) {
            ax[k] = ax[k] / sx * (float)OUT;
            ay[k] = ay[k] / sy * (float)OUT;
        }
    }

#pragma unroll
    for (int it = 0; it < 5; ++it) {
        float lmx = ax[0], lmy = ay[0];
#pragma unroll
        for (int k = 1; k < 8; ++k) { lmx = fmaxf(lmx, ax[k]); lmy = fmaxf(lmy, ay[k]); }
        const float mx = wave_max(lmx);
        const float my = wave_max(lmy);
        float tv = fminf(mx, my);
        if (it == 0) tv = fminf(tv, 4.0f);     // thr0 = DENSE*OUT/A

        float lsx = 0.0f, lsy = 0.0f;
#pragma unroll
        for (int k = 0; k < 8; ++k) {
            ax[k] = fminf(ax[k], tv); lsx += ax[k];
            ay[k] = fminf(ay[k], tv); lsy += ay[k];
        }
        const float sxs = wave_sum(lsx);
        const float sys = wave_sum(lsy);
        const float addx = ((float)OUT - sxs) * (1.0f / (float)AA);
        const float addy = ((float)OUT - sys) * (1.0f / (float)AA);
#pragma unroll
        for (int k = 0; k < 8; ++k) { ax[k] += addx; ay[k] += addy; }
    }

    float prex[8], prey[8];
    float runx = 0.0f, runy = 0.0f;
#pragma unroll
    for (int k = 0; k < 8; ++k) {
        runx += ax[k]; prex[k] = runx;
        runy += ay[k]; prey[k] = runy;
    }
    const float ltx = runx, lty = runy;
    float sxi = ltx, syi = lty;
#pragma unroll
    for (int off = 1; off < 64; off <<= 1) {
        const float tx = __shfl_up(sxi, off, 64);
        const float ty = __shfl_up(syi, off, 64);
        if (lane >= off) { sxi += tx; syi += ty; }
    }
    const float exx  = sxi - ltx;
    const float exy  = syi - lty;
    const float totx = __shfl(sxi, 63, 64);
    const float toty = __shfl(syi, 63, 64);

#pragma unroll
    for (int k = 0; k < 8; ++k) {
        csx[lane * 8 + k] = exx + prex[k];
        csy[lane * 8 + k] = exy + prey[k];
    }
    __syncthreads();

    const float stepx = totx * (1.0f / (float)OUT);
    const float stepy = toty * (1.0f / (float)OUT);

    float rx[8], ry[8];
#pragma unroll
    for (int k = 0; k < 8; ++k) {
        const int e = lane * 8 + k;
        {
            const float tk = ((float)e + 0.5f) * stepx;
            int lo = 0, hi = AA;
            while (lo < hi) {
                const int mid = (lo + hi) >> 1;
                if (csx[mid] < tk) lo = mid + 1; else hi = mid;
            }
            int j = lo > AA - 1 ? AA - 1 : lo;
            const float cp   = (j > 0) ? csx[j - 1] : 0.0f;
            const float dens = csx[j] - cp;
            const float p    = (float)j + (tk - cp) / fmaxf(dens, 1e-6f);
            rx[k] = 2.0f * p / (float)AA - 1.0f;
        }
        {
            const float tk = ((float)e + 0.5f) * stepy;
            int lo = 0, hi = AA;
            while (lo < hi) {
                const int mid = (lo + hi) >> 1;
                if (csy[mid] < tk) lo = mid + 1; else hi = mid;
            }
            int j = lo > AA - 1 ? AA - 1 : lo;
            const float cp   = (j > 0) ? csy[j - 1] : 0.0f;
            const float dens = csy[j] - cp;
            const float p    = (float)j + (tk - cp) / fmaxf(dens, 1e-6f);
            ry[k] = 2.0f * p / (float)AA - 1.0f;
        }
    }

    float4* opx = (float4*)(px + n * OUT + lane * 8);
    float4* opy = (float4*)(py + n * OUT + lane * 8);
    opx[0] = make_float4(rx[0], rx[1], rx[2], rx[3]);
    opx[1] = make_float4(rx[4], rx[5], rx[6], rx[7]);
    opy[0] = make_float4(ry[0], ry[1], ry[2], ry[3]);
    opy[1] = make_float4(ry[4], ry[5], ry[6], ry[7]);
}

// ---------------- kernel 2: grid build + bilinear sample -------------------
// R7 structure (staged rows, nontemporal outputs, hoisted px/grid) with ONE
// change: the 4-corner LDS gather per (output,c) becomes 2 paired reads of
// adjacent floats (&lrow[..][min(x0,510)] + [0],[1]) -> AMDGPU load-store
// optimizer fuses each pair into ds_read2_b32 offset0:0 offset1:1, halving
// DS instruction count (96 -> 48 wave-instrs per block). x0==511 edge
// (x1==x0) handled by a select: v00=v01=pair[1].
__global__ __launch_bounds__(256) void sample_kernel(
    const float* __restrict__ data, const float* __restrict__ px,
    const float* __restrict__ py, float* __restrict__ sampled,
    float2* __restrict__ grid)
{
    __shared__ float lrow[6][WW];   // 12 KB: rows (y0,c0..2), (y1,c0..2)

    const int bid = blockIdx.x;          // n*OUT + i
    const int n   = bid >> 9;            // / 512
    const int i   = bid & (OUT - 1);
    const int tid = threadIdx.x;

    const float gy  = py[n * OUT + i];
    // hoisted px loads (independent of staging)
    const float gx0 = px[n * OUT + tid];
    const float gx1 = px[n * OUT + tid + 256];

    const float iy  = (gy + 1.0f) * 0.5f * (float)(HH - 1);
    const float y0f = floorf(iy);
    const float wy  = iy - y0f;
    int y0 = (int)y0f;
    y0 = max(0, min(y0, HH - 1));
    const int y1 = min(y0 + 1, HH - 1);
    const float omwy = 1.0f - wy;

    const float* dbase = data + (size_t)n * NC * HH * WW;

    // stage 6 rows: 768 float4s over 256 threads (3 each), coalesced
#pragma unroll
    for (int k = 0; k < 3; ++k) {
        const int idx = tid + k * 256;       // 0..767
        const int row = idx >> 7;            // 0..5 (128 float4 per row)
        const int q   = idx & 127;           // float4 index within row
        const int c   = (row < 3) ? row : row - 3;
        const int y   = (row < 3) ? y0 : y1;
        const float4 v = ((const float4*)(dbase + ((size_t)c * HH + y) * WW))[q];
        ((float4*)&lrow[row][0])[q] = v;
    }

    // grid stores before the barrier: independent of LDS, overlap staging
    vf2* gbase2 = (vf2*)(grid + ((size_t)n * OUT + i) * OUT);
    {
        vf2 g0; g0.x = gx0; g0.y = gy;
        vf2 g1; g1.x = gx1; g1.y = gy;
        __builtin_nontemporal_store(g0, gbase2 + tid);
        __builtin_nontemporal_store(g1, gbase2 + tid + 256);
    }

    __syncthreads();

    float* sbase = sampled + (size_t)n * NC * HH * WW + (size_t)i * WW;

#pragma unroll
    for (int rep = 0; rep < 2; ++rep) {
        const int j = tid + rep * 256;
        const float gx  = (rep == 0) ? gx0 : gx1;
        const float ix  = (gx + 1.0f) * 0.5f * (float)(WW - 1);
        const float x0f = floorf(ix);
        const float wx  = ix - x0f;
        int x0 = (int)x0f;
        x0 = max(0, min(x0, WW - 1));
        const float omwx = 1.0f - wx;

        const int  xp = min(x0, WW - 2);     // paired-read base (4B aligned)
        const bool hi = (x0 == WW - 1);      // x1 == x0 == 511 edge

#pragma unroll
        for (int c = 0; c < NC; ++c) {
            const float* p0 = &lrow[c][xp];
            const float* p1 = &lrow[3 + c][xp];
            const float u0 = p0[0], u1 = p0[1];   // -> ds_read2_b32
            const float w0 = p1[0], w1 = p1[1];   // -> ds_read2_b32
            const float v00 = hi ? u1 : u0;
            const float v01 = u1;
            const float v10 = hi ? w1 : w0;
            const float v11 = w1;
            const float top = v00 * omwx + v01 * wx;
            const float bot = v10 * omwx + v11 * wx;
            const float r   = top * omwy + bot * wy;
            __builtin_nontemporal_store(r, sbase + (size_t)c * HH * WW + j);
        }
    }
}

extern "C" void kernel_launch(void* const* d_in, const int* in_sizes, int n_in,
                              void* d_out, int out_size, void* d_ws, size_t ws_size,
                              hipStream_t stream) {
    const float* data = (const float*)d_in[0];
    const float* attx = (const float*)d_in[1];
    const float* atty = (const float*)d_in[2];

    float* px = (float*)d_ws;                 // NB*OUT floats
    float* py = px + NB * OUT;                // NB*OUT floats

    float*  out     = (float*)d_out;
    float*  sampled = out;                                        // (N,C,H,W)
    float2* grid    = (float2*)(out + (size_t)NB * NC * HH * WW); // (N,H,W,2)

    clip_cdf_kernel<<<NB, 64, 0, stream>>>(attx, atty, px, py);
    sample_kernel<<<NB * OUT, 256, 0, stream>>>(data, px, py, sampled, grid);
}